// Round 1
// baseline (123.827 us; speedup 1.0000x reference)
//
#include <hip/hip_runtime.h>

// Problem constants (KANLayer): B=1024, I=128, O=128, H=5
#define Bsz 1024
#define Isz 128
#define Osz 128
#define Hsz 5
#define PSTRIDE 48     // packed per-edge param record: 46 floats + 2 pad (192 B, 16B aligned)
#define BT 256         // batch tile per block (== blockDim.x)
#define IC 64          // i-chunk staged in LDS
#define XSTR (BT + 1)  // LDS row stride (pad +1 -> conflict-free transpose write)

// ---------------------------------------------------------------------------
// Prologue: gather the 6 param arrays into one aligned [O*I][48] record so the
// main loop's wave-uniform param fetch becomes 3x s_load_dwordx16.
// ---------------------------------------------------------------------------
__global__ __launch_bounds__(256)
void repack_kernel(const float* __restrict__ W1, const float* __restrict__ B1,
                   const float* __restrict__ W2, const float* __restrict__ B2,
                   const float* __restrict__ W3, const float* __restrict__ B3,
                   float* __restrict__ P) {
    int idx = blockIdx.x * 256 + threadIdx.x;   // e*48 + s
    if (idx >= Osz * Isz * PSTRIDE) return;
    int e = idx / PSTRIDE;
    int s = idx - e * PSTRIDE;
    float v = 0.0f;
    if (s < 5)        v = W1[e * 5 + s];
    else if (s < 10)  v = B1[e * 5 + (s - 5)];
    else if (s < 35)  v = W2[e * 25 + (s - 10)];
    else if (s < 40)  v = B2[e * 5 + (s - 35)];
    else if (s < 45)  v = W3[e * 5 + (s - 40)];
    else if (s == 45) v = B3[e];
    P[idx] = v;
}

// ---------------------------------------------------------------------------
// Main kernel: one block = (o, batch-tile of 256). Each thread owns one (b,o),
// loops all i. Params are wave-uniform -> scalar loads. x staged transposed in
// LDS per 64-i chunk (coalesced global read, conflict-free LDS).
// ---------------------------------------------------------------------------
template <bool PACKED>
__global__ __launch_bounds__(256, 2)
void kan_kernel(const float* __restrict__ x, const float* __restrict__ P,
                const float* __restrict__ W1, const float* __restrict__ B1,
                const float* __restrict__ W2, const float* __restrict__ B2,
                const float* __restrict__ W3, const float* __restrict__ B3,
                float* __restrict__ out) {
    __shared__ float xs[IC * XSTR];

    const int tid = threadIdx.x;
    const int o   = blockIdx.x & (Osz - 1);
    const int b0  = (blockIdx.x >> 7) * BT;

    // Decompose staging index once: k = tid + 256*j -> r = rbase + 4j, c fixed.
    const int c_st = tid & (IC - 1);
    const int r_st = tid >> 6;

    float acc = 0.0f;

    for (int i0 = 0; i0 < Isz; i0 += IC) {
        __syncthreads();  // previous chunk's readers done before overwrite
        #pragma unroll
        for (int j = 0; j < (BT * IC) / 256; ++j) {
            const int r = r_st + 4 * j;
            xs[c_st * XSTR + r] = x[(b0 + r) * Isz + i0 + c_st];
        }
        __syncthreads();

        #pragma unroll 2
        for (int il = 0; il < IC; ++il) {
            const int i = i0 + il;
            const int e = o * Isz + i;

            float w1[Hsz], b1[Hsz], w2[Hsz * Hsz], b2[Hsz], w3[Hsz], b3v;
            if constexpr (PACKED) {
                const float* __restrict__ pp = P + (size_t)e * PSTRIDE;
                #pragma unroll
                for (int h = 0; h < Hsz; ++h) { w1[h] = pp[h]; b1[h] = pp[5 + h]; }
                #pragma unroll
                for (int j = 0; j < Hsz * Hsz; ++j) w2[j] = pp[10 + j];
                #pragma unroll
                for (int h = 0; h < Hsz; ++h) { b2[h] = pp[35 + h]; w3[h] = pp[40 + h]; }
                b3v = pp[45];
            } else {
                #pragma unroll
                for (int h = 0; h < Hsz; ++h) {
                    w1[h] = W1[e * Hsz + h];
                    b1[h] = B1[e * Hsz + h];
                    b2[h] = B2[e * Hsz + h];
                    w3[h] = W3[e * Hsz + h];
                }
                #pragma unroll
                for (int j = 0; j < Hsz * Hsz; ++j) w2[j] = W2[e * Hsz * Hsz + j];
                b3v = B3[e];
            }

            const float a = xs[il * XSTR + tid];

            float h1[Hsz];
            #pragma unroll
            for (int h = 0; h < Hsz; ++h) {
                float v = fmaf(a, w1[h], b1[h]);
                h1[h] = fmaxf(v, 0.01f * v);  // leaky_relu(0.01)
            }
            float y = b3v;
            #pragma unroll
            for (int k = 0; k < Hsz; ++k) {
                float s = b2[k];
                #pragma unroll
                for (int h = 0; h < Hsz; ++h)
                    s = fmaf(h1[h], w2[k * Hsz + h], s);
                s = fmaxf(s, 0.01f * s);
                y = fmaf(s, w3[k], y);
            }
            acc += y;
        }
    }

    out[(b0 + tid) * Osz + o] = acc;
}

extern "C" void kernel_launch(void* const* d_in, const int* in_sizes, int n_in,
                              void* d_out, int out_size, void* d_ws, size_t ws_size,
                              hipStream_t stream) {
    const float* x  = (const float*)d_in[0];
    const float* W1 = (const float*)d_in[1];
    const float* B1 = (const float*)d_in[2];
    const float* W2 = (const float*)d_in[3];
    const float* B2 = (const float*)d_in[4];
    const float* W3 = (const float*)d_in[5];
    const float* B3 = (const float*)d_in[6];
    float* out = (float*)d_out;

    const size_t packed_bytes = (size_t)Osz * Isz * PSTRIDE * sizeof(float);  // 3 MiB
    const dim3 grid((Bsz / BT) * Osz);  // 512 blocks
    const dim3 block(BT);

    if (ws_size >= packed_bytes) {
        float* P = (float*)d_ws;
        const int n = Osz * Isz * PSTRIDE;
        repack_kernel<<<dim3((n + 255) / 256), dim3(256), 0, stream>>>(W1, B1, W2, B2, W3, B3, P);
        kan_kernel<true><<<grid, block, 0, stream>>>(x, P, W1, B1, W2, B2, W3, B3, out);
    } else {
        kan_kernel<false><<<grid, block, 0, stream>>>(x, nullptr, W1, B1, W2, B2, W3, B3, out);
    }
}

// Round 2
// 114.367 us; speedup vs baseline: 1.0827x; 1.0827x over previous
//
#include <hip/hip_runtime.h>

// Problem constants (KANLayer): B=1024, I=128, O=128, H=5
#define Bsz 1024
#define Isz 128
#define Osz 128
#define Hsz 5
#define PSTRIDE 48     // packed per-edge param record: 46 floats + 2 pad (192 B, 16B aligned)
#define BT 256         // batch tile per block (== blockDim.x)
#define ICHUNK 32      // i-slice per block (I/ICHUNK = 4 partial-sum blocks per (b,o))

// ---------------------------------------------------------------------------
// Prologue: gather the 6 param arrays into one aligned [O*I][48] record so the
// main loop's wave-uniform param fetch becomes 3x s_load_dwordx16.
// ---------------------------------------------------------------------------
__global__ __launch_bounds__(256)
void repack_kernel(const float* __restrict__ W1, const float* __restrict__ B1,
                   const float* __restrict__ W2, const float* __restrict__ B2,
                   const float* __restrict__ W3, const float* __restrict__ B3,
                   float* __restrict__ P) {
    int idx = blockIdx.x * 256 + threadIdx.x;   // e*48 + s
    if (idx >= Osz * Isz * PSTRIDE) return;
    int e = idx / PSTRIDE;
    int s = idx - e * PSTRIDE;
    float v = 0.0f;
    if (s < 5)        v = W1[e * 5 + s];
    else if (s < 10)  v = B1[e * 5 + (s - 5)];
    else if (s < 35)  v = W2[e * 25 + (s - 10)];
    else if (s < 40)  v = B2[e * 5 + (s - 35)];
    else if (s < 45)  v = W3[e * 5 + (s - 40)];
    else if (s == 45) v = B3[e];
    P[idx] = v;
}

// ---------------------------------------------------------------------------
// Main kernel. Block = (o, batch-tile of 256, i-chunk of 32). Each thread owns
// one (b,o), loops its 32 i's with x held in registers (8x float4, L2-resident
// re-reads), params wave-uniform -> scalar loads. Partial sum combined via one
// fp32 atomicAdd per thread (out pre-zeroed by memset).
// Grid = 128 o * 4 btile * 4 ichunk = 2048 blocks -> up to 8 blocks/CU.
// ---------------------------------------------------------------------------
__global__ __launch_bounds__(256, 4)
void kan_kernel(const float* __restrict__ x, const float* __restrict__ P,
                float* __restrict__ out) {
    const int tid = threadIdx.x;
    const int o   = blockIdx.x & (Osz - 1);          // fastest: 128 consecutive
    const int ic  = (blockIdx.x >> 7) & 3;           // blocks share one x-slice
    const int b0  = (blockIdx.x >> 9) * BT;
    const int i0  = ic * ICHUNK;

    const int b = b0 + tid;

    // Own x slice: 32 floats, 128B-aligned.
    float4 xr[ICHUNK / 4];
    const float4* xv = (const float4*)(x + (size_t)b * Isz + i0);
    #pragma unroll
    for (int j = 0; j < ICHUNK / 4; ++j) xr[j] = xv[j];

    float acc = 0.0f;

    #pragma unroll
    for (int jj = 0; jj < ICHUNK / 4; ++jj) {
        const float av[4] = {xr[jj].x, xr[jj].y, xr[jj].z, xr[jj].w};
        #pragma unroll
        for (int q = 0; q < 4; ++q) {
            const int il = jj * 4 + q;
            const int e  = o * Isz + i0 + il;
            const float* __restrict__ pp = P + (size_t)e * PSTRIDE;

            // Wave-uniform param record (46 floats) -> scalar loads.
            float w1[Hsz], b1[Hsz], w2[Hsz * Hsz], b2[Hsz], w3[Hsz];
            #pragma unroll
            for (int h = 0; h < Hsz; ++h) { w1[h] = pp[h]; b1[h] = pp[5 + h]; }
            #pragma unroll
            for (int j = 0; j < Hsz * Hsz; ++j) w2[j] = pp[10 + j];
            #pragma unroll
            for (int h = 0; h < Hsz; ++h) { b2[h] = pp[35 + h]; w3[h] = pp[40 + h]; }
            const float b3v = pp[45];

            const float a = av[q];

            float h1[Hsz];
            #pragma unroll
            for (int h = 0; h < Hsz; ++h) {
                float v = fmaf(a, w1[h], b1[h]);
                h1[h] = fmaxf(v, 0.01f * v);  // leaky_relu(0.01)
            }
            float y = b3v;
            #pragma unroll
            for (int k = 0; k < Hsz; ++k) {
                float s = b2[k];
                #pragma unroll
                for (int h = 0; h < Hsz; ++h)
                    s = fmaf(h1[h], w2[k * Hsz + h], s);
                s = fmaxf(s, 0.01f * s);
                y = fmaf(s, w3[k], y);
            }
            acc += y;
        }
    }

    atomicAdd(&out[(size_t)b * Osz + o], acc);
}

extern "C" void kernel_launch(void* const* d_in, const int* in_sizes, int n_in,
                              void* d_out, int out_size, void* d_ws, size_t ws_size,
                              hipStream_t stream) {
    const float* x  = (const float*)d_in[0];
    const float* W1 = (const float*)d_in[1];
    const float* B1 = (const float*)d_in[2];
    const float* W2 = (const float*)d_in[3];
    const float* B2 = (const float*)d_in[4];
    const float* W3 = (const float*)d_in[5];
    const float* B3 = (const float*)d_in[6];
    float* out = (float*)d_out;
    float* P   = (float*)d_ws;   // 3 MiB packed params (ws is re-poisoned each call)

    // Repack params every call (d_ws is re-poisoned before every launch).
    const int n = Osz * Isz * PSTRIDE;
    repack_kernel<<<dim3((n + 255) / 256), dim3(256), 0, stream>>>(W1, B1, W2, B2, W3, B3, P);

    // out accumulates 4 i-chunk partials via atomicAdd -> must start at zero.
    hipMemsetAsync(out, 0, (size_t)out_size * sizeof(float), stream);

    const dim3 grid(Osz * (Bsz / BT) * (Isz / ICHUNK));  // 2048 blocks
    kan_kernel<<<grid, dim3(BT), 0, stream>>>(x, P, out);
}